// Round 4
// baseline (40.494 us; speedup 1.0000x reference)
//
#include <hip/hip_runtime.h>

#define B_ROWS 256
#define NT     1024          // 16 waves per block, one block per row

// ---------------------------------------------------------------------------
// One block per row: stream the row (float4, unroll 4), block-reduce the five
// sums {x, y, xy, x^2, y^2}, compute (1 - pearson)/B in double, and
// atomicAdd the scalar into out[0]. No second kernel, no fences.
// ---------------------------------------------------------------------------
__global__ __launch_bounds__(NT) void pearson_row(
    const float* __restrict__ preds,
    const float* __restrict__ labels,
    float* __restrict__ out,     // zeroed by hipMemsetAsync each call
    int N)
{
    const int row = blockIdx.x;
    const int tid = threadIdx.x;

    const int n4   = N >> 2;          // 25000 float4 per row (N % 4 == 0)
    const int full = n4 / NT;         // 24
    const int rem  = n4 - full * NT;  // 424

    const float4* p4 = reinterpret_cast<const float4*>(preds  + (size_t)row * N);
    const float4* l4 = reinterpret_cast<const float4*>(labels + (size_t)row * N);

    float sx = 0.f, sy = 0.f, sxy = 0.f, sxx = 0.f, syy = 0.f;

    int i = tid;
#pragma unroll 4
    for (int k = 0; k < full; ++k, i += NT) {
        float4 a = p4[i];
        float4 b = l4[i];
        sx += a.x; sy += b.x; sxy = fmaf(a.x, b.x, sxy); sxx = fmaf(a.x, a.x, sxx); syy = fmaf(b.x, b.x, syy);
        sx += a.y; sy += b.y; sxy = fmaf(a.y, b.y, sxy); sxx = fmaf(a.y, a.y, sxx); syy = fmaf(b.y, b.y, syy);
        sx += a.z; sy += b.z; sxy = fmaf(a.z, b.z, sxy); sxx = fmaf(a.z, a.z, sxx); syy = fmaf(b.z, b.z, syy);
        sx += a.w; sy += b.w; sxy = fmaf(a.w, b.w, sxy); sxx = fmaf(a.w, a.w, sxx); syy = fmaf(b.w, b.w, syy);
    }
    if (tid < rem) {
        float4 a = p4[full * NT + tid];
        float4 b = l4[full * NT + tid];
        sx += a.x; sy += b.x; sxy = fmaf(a.x, b.x, sxy); sxx = fmaf(a.x, a.x, sxx); syy = fmaf(b.x, b.x, syy);
        sx += a.y; sy += b.y; sxy = fmaf(a.y, b.y, sxy); sxx = fmaf(a.y, a.y, sxx); syy = fmaf(b.y, b.y, syy);
        sx += a.z; sy += b.z; sxy = fmaf(a.z, b.z, sxy); sxx = fmaf(a.z, a.z, sxx); syy = fmaf(b.z, b.z, syy);
        sx += a.w; sy += b.w; sxy = fmaf(a.w, b.w, sxy); sxx = fmaf(a.w, a.w, sxx); syy = fmaf(b.w, b.w, syy);
    }

    // wave-64 butterfly reduction
    for (int o = 32; o > 0; o >>= 1) {
        sx  += __shfl_down(sx,  o, 64);
        sy  += __shfl_down(sy,  o, 64);
        sxy += __shfl_down(sxy, o, 64);
        sxx += __shfl_down(sxx, o, 64);
        syy += __shfl_down(syy, o, 64);
    }

    __shared__ float red[NT / 64][5];   // 16 waves
    const int wave = tid >> 6;
    const int lane = tid & 63;
    if (lane == 0) {
        red[wave][0] = sx;  red[wave][1] = sy;  red[wave][2] = sxy;
        red[wave][3] = sxx; red[wave][4] = syy;
    }
    __syncthreads();

    if (tid == 0) {
        double acc0 = 0.0, acc1 = 0.0, acc2 = 0.0, acc3 = 0.0, acc4 = 0.0;
#pragma unroll
        for (int w = 0; w < NT / 64; ++w) {
            acc0 += (double)red[w][0];
            acc1 += (double)red[w][1];
            acc2 += (double)red[w][2];
            acc3 += (double)red[w][3];
            acc4 += (double)red[w][4];
        }
        const double n   = (double)N;
        const double num = n * acc2 - acc0 * acc1;
        const double den = sqrt((n * acc3 - acc0 * acc0) * (n * acc4 - acc1 * acc1));
        const double val = (1.0 - num / den) / (double)B_ROWS;
        atomicAdd(out, (float)val);      // 256 adds to one address, device scope
    }
}

// ---------------------------------------------------------------------------
extern "C" void kernel_launch(void* const* d_in, const int* in_sizes, int n_in,
                              void* d_out, int out_size, void* d_ws, size_t ws_size,
                              hipStream_t stream)
{
    const float* preds  = (const float*)d_in[0];
    const float* labels = (const float*)d_in[1];
    // d_in[2] = subject (scalar int), unused by the math.

    const int N = in_sizes[0] / B_ROWS;   // 100000
    float* out = (float*)d_out;

    hipMemsetAsync(out, 0, sizeof(float), stream);   // in-graph, replay-safe
    pearson_row<<<B_ROWS, NT, 0, stream>>>(preds, labels, out, N);
}

// Round 5
// 38.299 us; speedup vs baseline: 1.0573x; 1.0573x over previous
//
#include <hip/hip_runtime.h>

#define B_ROWS   256
#define SPLIT    8                      // segments (blocks) per row
#define NTHREADS 256                    // 4 waves
#define NBLOCKS  (B_ROWS * SPLIT)       // 2048 = 8 blocks/CU, 32 waves/CU

// ws layout (SoA): component j in ws[j*NBLOCKS + bid], j in {0..4}

// ---------------------------------------------------------------------------
// Kernel 1: per-(row,segment) partial sums of {x, y, xy, x^2, y^2}.
// R1 grid/occupancy (2048x256, proven 74% occ) + R4 loop body (unroll 4,
// 8 float4 loads in flight — proven 4.5% faster streaming under rocprof).
// ---------------------------------------------------------------------------
__global__ __launch_bounds__(NTHREADS, 8) void pearson_partial(
    const float* __restrict__ preds,
    const float* __restrict__ labels,
    float* __restrict__ ws,   // [5][NBLOCKS]
    int N)
{
    const int bid = blockIdx.x;
    const int row = bid >> 3;            // / SPLIT
    const int seg = bid & (SPLIT - 1);
    const int tid = threadIdx.x;

    const int n4      = N >> 2;          // 25000 float4 per row (N % 4 == 0)
    const int per_seg = n4 / SPLIT;      // 3125 (exact)
    const int begin   = seg * per_seg;

    const int full = per_seg / NTHREADS;             // 12
    const int rem  = per_seg - full * NTHREADS;      // 53

    const float4* p4 = reinterpret_cast<const float4*>(preds  + (size_t)row * N);
    const float4* l4 = reinterpret_cast<const float4*>(labels + (size_t)row * N);

    float sx = 0.f, sy = 0.f, sxy = 0.f, sxx = 0.f, syy = 0.f;

    int i = begin + tid;
#pragma unroll 4
    for (int k = 0; k < full; ++k, i += NTHREADS) {
        float4 a = p4[i];
        float4 b = l4[i];
        sx += a.x; sy += b.x; sxy = fmaf(a.x, b.x, sxy); sxx = fmaf(a.x, a.x, sxx); syy = fmaf(b.x, b.x, syy);
        sx += a.y; sy += b.y; sxy = fmaf(a.y, b.y, sxy); sxx = fmaf(a.y, a.y, sxx); syy = fmaf(b.y, b.y, syy);
        sx += a.z; sy += b.z; sxy = fmaf(a.z, b.z, sxy); sxx = fmaf(a.z, a.z, sxx); syy = fmaf(b.z, b.z, syy);
        sx += a.w; sy += b.w; sxy = fmaf(a.w, b.w, sxy); sxx = fmaf(a.w, a.w, sxx); syy = fmaf(b.w, b.w, syy);
    }
    if (tid < rem) {
        float4 a = p4[begin + full * NTHREADS + tid];
        float4 b = l4[begin + full * NTHREADS + tid];
        sx += a.x; sy += b.x; sxy = fmaf(a.x, b.x, sxy); sxx = fmaf(a.x, a.x, sxx); syy = fmaf(b.x, b.x, syy);
        sx += a.y; sy += b.y; sxy = fmaf(a.y, b.y, sxy); sxx = fmaf(a.y, a.y, sxx); syy = fmaf(b.y, b.y, syy);
        sx += a.z; sy += b.z; sxy = fmaf(a.z, b.z, sxy); sxx = fmaf(a.z, a.z, sxx); syy = fmaf(b.z, b.z, syy);
        sx += a.w; sy += b.w; sxy = fmaf(a.w, b.w, sxy); sxx = fmaf(a.w, a.w, sxx); syy = fmaf(b.w, b.w, syy);
    }

    // wave-64 butterfly reduction
    for (int o = 32; o > 0; o >>= 1) {
        sx  += __shfl_down(sx,  o, 64);
        sy  += __shfl_down(sy,  o, 64);
        sxy += __shfl_down(sxy, o, 64);
        sxx += __shfl_down(sxx, o, 64);
        syy += __shfl_down(syy, o, 64);
    }

    __shared__ float red[4][5];
    const int wave = tid >> 6;
    const int lane = tid & 63;
    if (lane == 0) {
        red[wave][0] = sx;  red[wave][1] = sy;  red[wave][2] = sxy;
        red[wave][3] = sxx; red[wave][4] = syy;
    }
    __syncthreads();

    if (tid == 0) {
        ws[0 * NBLOCKS + bid] = red[0][0] + red[1][0] + red[2][0] + red[3][0];
        ws[1 * NBLOCKS + bid] = red[0][1] + red[1][1] + red[2][1] + red[3][1];
        ws[2 * NBLOCKS + bid] = red[0][2] + red[1][2] + red[2][2] + red[3][2];
        ws[3 * NBLOCKS + bid] = red[0][3] + red[1][3] + red[2][3] + red[3][3];
        ws[4 * NBLOCKS + bid] = red[0][4] + red[1][4] + red[2][4] + red[3][4];
    }
}

// ---------------------------------------------------------------------------
// Kernel 2: combine SPLIT partials per row (double), compute 1 - pearson,
// mean over rows. 1 block x 256 threads (one thread per row), SoA float4 loads.
// ---------------------------------------------------------------------------
__global__ __launch_bounds__(NTHREADS) void pearson_final(
    const float* __restrict__ ws,
    float* __restrict__ out,
    int N)
{
    const int t = threadIdx.x;   // row index (NTHREADS == B_ROWS)
    const float4* ws4 = reinterpret_cast<const float4*>(ws);

    float4 v[5][2];
#pragma unroll
    for (int j = 0; j < 5; ++j) {
        v[j][0] = ws4[j * (NBLOCKS / 4) + 2 * t];
        v[j][1] = ws4[j * (NBLOCKS / 4) + 2 * t + 1];
    }

    double acc[5];
#pragma unroll
    for (int j = 0; j < 5; ++j) {
        acc[j] = (double)v[j][0].x + (double)v[j][0].y + (double)v[j][0].z + (double)v[j][0].w
               + (double)v[j][1].x + (double)v[j][1].y + (double)v[j][1].z + (double)v[j][1].w;
    }

    const double n   = (double)N;
    const double num = n * acc[2] - acc[0] * acc[1];
    const double den = sqrt((n * acc[3] - acc[0] * acc[0]) * (n * acc[4] - acc[1] * acc[1]));
    double val = 1.0 - num / den;

    for (int o = 32; o > 0; o >>= 1)
        val += __shfl_down(val, o, 64);

    __shared__ double dred[4];
    const int wave = t >> 6;
    const int lane = t & 63;
    if (lane == 0) dred[wave] = val;
    __syncthreads();

    if (t == 0)
        out[0] = (float)((dred[0] + dred[1] + dred[2] + dred[3]) / (double)B_ROWS);
}

// ---------------------------------------------------------------------------
extern "C" void kernel_launch(void* const* d_in, const int* in_sizes, int n_in,
                              void* d_out, int out_size, void* d_ws, size_t ws_size,
                              hipStream_t stream)
{
    const float* preds  = (const float*)d_in[0];
    const float* labels = (const float*)d_in[1];
    // d_in[2] = subject (scalar int), unused by the math.

    const int N = in_sizes[0] / B_ROWS;   // 100000

    float* ws  = (float*)d_ws;            // 5*NBLOCKS floats = 40 KiB
    float* out = (float*)d_out;

    pearson_partial<<<NBLOCKS, NTHREADS, 0, stream>>>(preds, labels, ws, N);
    pearson_final<<<1, NTHREADS, 0, stream>>>(ws, out, N);
}

// Round 6
// 37.771 us; speedup vs baseline: 1.0721x; 1.0140x over previous
//
#include <hip/hip_runtime.h>

#define B_ROWS   256
#define SPLIT    8          // blocks per row
#define NTHREADS 256        // 4 waves
#define NBLOCKS  (B_ROWS * SPLIT)

// Proven-best configuration (round 1, 37.60 us timed):
// - 2048 blocks x 256 threads, 16 VGPR, no unroll pragma (12 iters/thread,
//   2 float4 loads in flight/wave; occupancy 32 waves/CU hides the rest)
// - two-kernel structure: streaming partials + tiny finalizer
//   (fusion alternatives measured worse: last-block fence storm 103 us,
//    1-block/row atomic 40.5 us; finalizer internals don't matter — tail
//    is launch-node overhead ~4 us)

// ---------------------------------------------------------------------------
// Kernel 1: per-(row,segment) partial sums of {x, y, xy, x^2, y^2}.
// ---------------------------------------------------------------------------
__global__ __launch_bounds__(NTHREADS) void pearson_partial(
    const float* __restrict__ preds,
    const float* __restrict__ labels,
    float* __restrict__ ws,   // [NBLOCKS][5]
    int N)
{
    const int row = blockIdx.x / SPLIT;
    const int seg = blockIdx.x % SPLIT;
    const int tid = threadIdx.x;

    const int n4      = N / 4;         // 25000 float4 per row (N % 4 == 0)
    const int per_seg = n4 / SPLIT;    // 3125 (exact)
    const int begin   = seg * per_seg;
    const int end     = begin + per_seg;

    const float4* p4 = reinterpret_cast<const float4*>(preds  + (size_t)row * N);
    const float4* l4 = reinterpret_cast<const float4*>(labels + (size_t)row * N);

    float sx = 0.f, sy = 0.f, sxy = 0.f, sxx = 0.f, syy = 0.f;

    for (int i = begin + tid; i < end; i += NTHREADS) {
        float4 a = p4[i];
        float4 b = l4[i];
        sx += a.x; sy += b.x; sxy = fmaf(a.x, b.x, sxy); sxx = fmaf(a.x, a.x, sxx); syy = fmaf(b.x, b.x, syy);
        sx += a.y; sy += b.y; sxy = fmaf(a.y, b.y, sxy); sxx = fmaf(a.y, a.y, sxx); syy = fmaf(b.y, b.y, syy);
        sx += a.z; sy += b.z; sxy = fmaf(a.z, b.z, sxy); sxx = fmaf(a.z, a.z, sxx); syy = fmaf(b.z, b.z, syy);
        sx += a.w; sy += b.w; sxy = fmaf(a.w, b.w, sxy); sxx = fmaf(a.w, a.w, sxx); syy = fmaf(b.w, b.w, syy);
    }

    // wave-64 butterfly reduction
    for (int o = 32; o > 0; o >>= 1) {
        sx  += __shfl_down(sx,  o, 64);
        sy  += __shfl_down(sy,  o, 64);
        sxy += __shfl_down(sxy, o, 64);
        sxx += __shfl_down(sxx, o, 64);
        syy += __shfl_down(syy, o, 64);
    }

    __shared__ float red[4][5];
    const int wave = tid >> 6;
    const int lane = tid & 63;
    if (lane == 0) {
        red[wave][0] = sx;  red[wave][1] = sy;  red[wave][2] = sxy;
        red[wave][3] = sxx; red[wave][4] = syy;
    }
    __syncthreads();

    if (tid == 0) {
        float* w = ws + (size_t)blockIdx.x * 5;
        w[0] = red[0][0] + red[1][0] + red[2][0] + red[3][0];
        w[1] = red[0][1] + red[1][1] + red[2][1] + red[3][1];
        w[2] = red[0][2] + red[1][2] + red[2][2] + red[3][2];
        w[3] = red[0][3] + red[1][3] + red[2][3] + red[3][3];
        w[4] = red[0][4] + red[1][4] + red[2][4] + red[3][4];
    }
}

// ---------------------------------------------------------------------------
// Kernel 2: combine SPLIT partials per row (double), compute 1 - pearson,
// mean over rows. 1 block x 256 threads (one thread per row).
// ---------------------------------------------------------------------------
__global__ __launch_bounds__(NTHREADS) void pearson_final(
    const float* __restrict__ ws,
    float* __restrict__ out,
    int N)
{
    const int t = threadIdx.x;   // row index

    double sx = 0.0, sy = 0.0, sxy = 0.0, sxx = 0.0, syy = 0.0;
#pragma unroll
    for (int s = 0; s < SPLIT; ++s) {
        const float* w = ws + ((size_t)t * SPLIT + s) * 5;
        sx  += (double)w[0];
        sy  += (double)w[1];
        sxy += (double)w[2];
        sxx += (double)w[3];
        syy += (double)w[4];
    }

    const double n   = (double)N;
    const double num = n * sxy - sx * sy;
    const double den = sqrt((n * sxx - sx * sx) * (n * syy - sy * sy));
    double val = 1.0 - num / den;

    for (int o = 32; o > 0; o >>= 1)
        val += __shfl_down(val, o, 64);

    __shared__ double red[4];
    const int wave = t >> 6;
    const int lane = t & 63;
    if (lane == 0) red[wave] = val;
    __syncthreads();

    if (t == 0) {
        double total = red[0] + red[1] + red[2] + red[3];
        out[0] = (float)(total / (double)B_ROWS);
    }
}

// ---------------------------------------------------------------------------
extern "C" void kernel_launch(void* const* d_in, const int* in_sizes, int n_in,
                              void* d_out, int out_size, void* d_ws, size_t ws_size,
                              hipStream_t stream)
{
    const float* preds  = (const float*)d_in[0];
    const float* labels = (const float*)d_in[1];
    // d_in[2] = subject (scalar int), unused by the math.

    const int N = in_sizes[0] / B_ROWS;   // 100000

    float* ws  = (float*)d_ws;            // NBLOCKS*5 floats = 40 KiB
    float* out = (float*)d_out;

    pearson_partial<<<NBLOCKS, NTHREADS, 0, stream>>>(preds, labels, ws, N);
    pearson_final<<<1, NTHREADS, 0, stream>>>(ws, out, N);
}